// Round 13
// baseline (137.258 us; speedup 1.0000x reference)
//
#include <hip/hip_runtime.h>
#include <hip/hip_fp8.h>
#include <hip/hip_fp16.h>
#include <stdint.h>

#define MARGIN 0.3f

constexpr int N = 8192;
constexpr int D = 512;
constexpr int BT = 64;                        // tile = 64 rows (one wave)
constexpr int NKB = D / 32;                   // 16 K-chunks of 32
constexpr int NT = N / BT;                    // 128 tiles per side
constexpr int NPAIR = NT * (NT + 1) / 2;      // 8256 unordered tile pairs
constexpr int WEDGE = NPAIR / 8;              // 1032 pairs per XCD wedge
constexpr float ESCALE = 16.0f;               // fp8 pre-scale
constexpr float INV_SC2 = 1.0f / (ESCALE * ESCALE);

typedef float f32x4 __attribute__((ext_vector_type(4)));

__device__ __forceinline__ unsigned char f2fp8(float f) {
  return __hip_fp8_e4m3(f).__x; // OCP e4m3fn, RNE+sat
}

// pack (minpos, maxneg) as half2 in a u32: lo16=min, hi16=max
__device__ __forceinline__ unsigned packMM(float mn, float mx) {
  unsigned short a = __half_as_ushort(__float2half(mn));
  unsigned short b = __half_as_ushort(__float2half(mx));
  return (unsigned)a | ((unsigned)b << 16);
}
__device__ __forceinline__ float unpLo(unsigned u) {
  return __half2float(__ushort_as_half((unsigned short)(u & 0xffff)));
}
__device__ __forceinline__ float unpHi(unsigned u) {
  return __half2float(__ushort_as_half((unsigned short)(u >> 16)));
}

// Decode pair q (16x16-super-tile-major lower triangle) -> (ti,tj), ti>=tj.
// Super-row SI: 256*SI off-diag pairs + 136 diag; base(SI) = 128*SI^2 + 8*SI.
__device__ __forceinline__ void pair_from_q(int q, int& ti, int& tj) {
  int SI = 0;
  while (128 * (SI + 1) * (SI + 1) + 8 * (SI + 1) <= q) ++SI;
  int r = q - (128 * SI * SI + 8 * SI);
  int i, j, SJ;
  if (r < 256 * SI) {        // off-diagonal super: full 16x16, row-major
    SJ = r >> 8;
    int w = r & 255;
    i = w >> 4;
    j = w & 15;
  } else {                   // diagonal super: triangular 136 pairs
    int d = r - 256 * SI;
    SJ = SI;
    i = 0;
    while ((i + 1) * (i + 2) / 2 <= d) ++i;
    j = d - i * (i + 1) / 2;
  }
  ti = SI * 16 + i;
  tj = SJ * 16 + j;
}

// Fragment-major e8 layout: byte (row,k) stored at
//   (row>>4)*8192 + (k>>5)*512 + (row&15)*32 + (k&31)

// ---- kernel 1: L2-normalize rows -> fp8 e4m3 (x16), fragment-major ----
__global__ __launch_bounds__(256) void normalize_rows(
    const float* __restrict__ emb, unsigned char* __restrict__ e8) {
  const int wave = threadIdx.x >> 6, lane = threadIdx.x & 63;
  const int row = blockIdx.x * 4 + wave;
  const float4* src = (const float4*)(emb + (size_t)row * D);
  float4 x0 = src[lane];
  float4 x1 = src[lane + 64];
  float ss = x0.x * x0.x + x0.y * x0.y + x0.z * x0.z + x0.w * x0.w +
             x1.x * x1.x + x1.y * x1.y + x1.z * x1.z + x1.w * x1.w;
#pragma unroll
  for (int m = 1; m < 64; m <<= 1) ss += __shfl_xor(ss, m, 64);
  const float r = rsqrtf(ss) * ESCALE;
  union { unsigned char b[8]; uint2 u; } o;
  o.b[0] = f2fp8(x0.x * r); o.b[1] = f2fp8(x0.y * r);
  o.b[2] = f2fp8(x0.z * r); o.b[3] = f2fp8(x0.w * r);
  o.b[4] = f2fp8(x1.x * r); o.b[5] = f2fp8(x1.y * r);
  o.b[6] = f2fp8(x1.z * r); o.b[7] = f2fp8(x1.w * r);
  const unsigned off = (unsigned)(row >> 4) * 8192 + (unsigned)(lane >> 2) * 512 +
                       (row & 15) * 32 + (lane & 3) * 8;
  *(uint2*)(e8 + off) = o.u;
}

// ---- kernel 2: single-wave fp8 Gram tile + batch-hard mining ----
// 8256 one-wave blocks (pair q = 1032*(b%8) + b/8: XCD-wedge, super-tile
// L2-local). No LDS, no barriers; depth-2 rotating register pipeline.
// Each pair writes its 64-row strips' (min,max) to uniquely-owned scr slots.
__global__ __launch_bounds__(64, 4) void bh_gemm_sym(
    const unsigned char* __restrict__ e8, const int* __restrict__ labels,
    unsigned* __restrict__ scr) {
  const int b = blockIdx.x;
  const int q = WEDGE * (b & 7) + (b >> 3);
  int ti, tj;
  pair_from_q(q, ti, tj);
  const int iBase = ti * BT, jBase = tj * BT; // block-uniform -> SGPRs
  const bool diag = (ti == tj);

  const int lane = threadIdx.x;
  const int quad = lane >> 4, n16 = lane & 15;
  const unsigned laneOff = (unsigned)n16 * 32 + (unsigned)quad * 8;

  const unsigned char* aP[4];
  const unsigned char* bP[4];
#pragma unroll
  for (int r = 0; r < 4; ++r) {
    aP[r] = e8 + (unsigned)(iBase + r * 16) * 512 + laneOff;
    bP[r] = e8 + (unsigned)(jBase + r * 16) * 512 + laneOff;
  }

  f32x4 acc[4][4];
#pragma unroll
  for (int r = 0; r < 4; ++r)
#pragma unroll
    for (int c = 0; c < 4; ++c) acc[r][c] = (f32x4)0.0f;

  long abuf[3][4], bbuf[3][4]; // 3-phase rotation, depth-2 prefetch
#pragma unroll
  for (int ph = 0; ph < 2; ++ph)
#pragma unroll
    for (int r = 0; r < 4; ++r) {
      abuf[ph][r] = *(const long*)(aP[r] + ph * 512);
      bbuf[ph][r] = *(const long*)(bP[r] + ph * 512);
    }

#pragma unroll
  for (int kb = 0; kb < NKB; ++kb) {
    const int cur = kb % 3;
    if (kb + 2 < NKB) {
      const int nxt = (kb + 2) % 3;
#pragma unroll
      for (int r = 0; r < 4; ++r) {
        abuf[nxt][r] = *(const long*)(aP[r] + (kb + 2) * 512);
        bbuf[nxt][r] = *(const long*)(bP[r] + (kb + 2) * 512);
      }
    }
#pragma unroll
    for (int r = 0; r < 4; ++r)
#pragma unroll
      for (int c = 0; c < 4; ++c)
        acc[r][c] = __builtin_amdgcn_mfma_f32_16x16x32_fp8_fp8(
            abuf[cur][r], bbuf[cur][c], acc[r][c], 0, 0, 0);
  }

  // ---- epilogue: batch-hard mining (similarity = acc / ESCALE^2) ----
  // C/D layout: row = r*16 + quad*4 + v, col = c*16 + n16
  int lj[4];
#pragma unroll
  for (int c = 0; c < 4; ++c) lj[c] = labels[jBase + c * 16 + n16];

  float cminp[4], cmaxn[4]; // col-side (transpose) mining, live across r
#pragma unroll
  for (int c = 0; c < 4; ++c) {
    cminp[c] = __builtin_inff();
    cmaxn[c] = -__builtin_inff();
  }

#pragma unroll
  for (int r = 0; r < 4; ++r) {
    const int rbase = r * 16 + quad * 4; // row offset within tile
    int4 li = *(const int4*)(labels + iBase + rbase);
    const int* lav = (const int*)&li;
    float minp[4], maxn[4];
#pragma unroll
    for (int v = 0; v < 4; ++v) {
      minp[v] = __builtin_inff();
      maxn[v] = -__builtin_inff();
    }
#pragma unroll
    for (int c = 0; c < 4; ++c) {
      const int col_ = c * 16 + n16;
#pragma unroll
      for (int v = 0; v < 4; ++v) {
        float s = acc[r][c][v] * INV_SC2;
        bool same = (lav[v] == lj[c]);
        float pv = same ? s : __builtin_inff();
        float nv = same ? -__builtin_inff() : s;
        if (diag && (rbase + v) == col_) pv = __builtin_inff(); // self
        minp[v] = fminf(minp[v], pv);
        maxn[v] = fmaxf(maxn[v], nv);
        cminp[c] = fminf(cminp[c], same ? s : __builtin_inff());
        cmaxn[c] = fmaxf(cmaxn[c], same ? -__builtin_inff() : s);
      }
    }
    // butterfly across the 16 n16-lanes sharing these 4 rows
#pragma unroll
    for (int m = 1; m <= 8; m <<= 1) {
#pragma unroll
      for (int v = 0; v < 4; ++v) {
        minp[v] = fminf(minp[v], __shfl_xor(minp[v], m, 64));
        maxn[v] = fmaxf(maxn[v], __shfl_xor(maxn[v], m, 64));
      }
    }
    if (n16 == 0) { // lanes 0,16,32,48 hold rows rbase..rbase+3
#pragma unroll
      for (int v = 0; v < 4; ++v)
        scr[(unsigned)(iBase + rbase + v) * 128 + tj] = packMM(minp[v], maxn[v]);
    }
  }

  // col-side (transpose mining): butterfly across the 4 quads
  if (!diag) {
#pragma unroll
    for (int m = 16; m <= 32; m <<= 1) {
#pragma unroll
      for (int c = 0; c < 4; ++c) {
        cminp[c] = fminf(cminp[c], __shfl_xor(cminp[c], m, 64));
        cmaxn[c] = fmaxf(cmaxn[c], __shfl_xor(cmaxn[c], m, 64));
      }
    }
    if (quad == 0) { // lanes 0..15 hold cols c*16 + n16
#pragma unroll
      for (int c = 0; c < 4; ++c)
        scr[(unsigned)(jBase + c * 16 + n16) * 128 + ti] = packMM(cminp[c], cmaxn[c]);
    }
  }
}

// ---- kernel 3: per-row reduce over 128 slots, then mean of relu ----
__global__ __launch_bounds__(256) void finalize_loss(
    const unsigned* __restrict__ scr, float* __restrict__ out) {
  const int row = blockIdx.x * 256 + threadIdx.x;
  const uint4* p = (const uint4*)(scr + (size_t)row * 128);
  float mn = __builtin_inff(), mx = -__builtin_inff();
#pragma unroll
  for (int i = 0; i < 32; ++i) {
    uint4 w = p[i];
    mn = fminf(fminf(fminf(mn, unpLo(w.x)), unpLo(w.y)), fminf(unpLo(w.z), unpLo(w.w)));
    mx = fmaxf(fmaxf(fmaxf(mx, unpHi(w.x)), unpHi(w.y)), fmaxf(unpHi(w.z), unpHi(w.w)));
  }
  float loss = mx - mn + MARGIN;       // hardest_pos - hardest_neg + margin
  float sum = loss > 0.f ? loss : 0.f; // relu(-inf) = 0 matches jnp
#pragma unroll
  for (int m = 1; m < 64; m <<= 1) sum += __shfl_xor(sum, m, 64);
  __shared__ float ws4[4];
  const int lane = threadIdx.x & 63, wave = threadIdx.x >> 6;
  if (lane == 0) ws4[wave] = sum;
  __syncthreads();
  if (threadIdx.x == 0)
    atomicAdd(out, (ws4[0] + ws4[1] + ws4[2] + ws4[3]) * (1.0f / N));
}

extern "C" void kernel_launch(void* const* d_in, const int* in_sizes, int n_in,
                              void* d_out, int out_size, void* d_ws, size_t ws_size,
                              hipStream_t stream) {
  const float* emb = (const float*)d_in[0];
  const int* labels = (const int*)d_in[1];
  float* out = (float*)d_out;

  unsigned char* e8 = (unsigned char*)d_ws;                    // [0, 4 MB): fp8 fragment-major
  unsigned* scr = (unsigned*)((char*)d_ws + (size_t)4 * 1024 * 1024); // [4, 8 MB): 8192x128 u32

  hipMemsetAsync(out, 0, sizeof(float), stream); // zero accumulator (d_out is poisoned)
  normalize_rows<<<N / 4, 256, 0, stream>>>(emb, e8);
  bh_gemm_sym<<<NPAIR, 64, 0, stream>>>(e8, labels, scr);
  finalize_loss<<<N / 256, 256, 0, stream>>>(scr, out);
}

// Round 14
// 114.014 us; speedup vs baseline: 1.2039x; 1.2039x over previous
//
#include <hip/hip_runtime.h>
#include <hip/hip_fp8.h>
#include <hip/hip_fp16.h>
#include <stdint.h>

#define MARGIN 0.3f

constexpr int N = 8192;
constexpr int D = 512;
constexpr int BM = 128, BN = 128;
constexpr int NKB = D / 32;                   // 16 K-chunks of 32
constexpr int NT = N / BM;                    // 64 tiles per side
constexpr int NPAIR = NT * (NT + 1) / 2;      // 2080 unordered tile pairs
constexpr int WEDGE = NPAIR / 8;              // 260 pairs per XCD wedge
constexpr float ESCALE = 16.0f;               // fp8 pre-scale
constexpr float INV_SC2 = 1.0f / (ESCALE * ESCALE);

typedef float f32x4 __attribute__((ext_vector_type(4)));

__device__ __forceinline__ unsigned char f2fp8(float f) {
  return __hip_fp8_e4m3(f).__x; // OCP e4m3fn, RNE+sat
}

// pack (minpos, maxneg) as half2 in a u32: lo16=min, hi16=max
__device__ __forceinline__ unsigned packMM(float mn, float mx) {
  unsigned short a = __half_as_ushort(__float2half(mn));
  unsigned short b = __half_as_ushort(__float2half(mx));
  return (unsigned)a | ((unsigned)b << 16);
}
__device__ __forceinline__ float unpLo(unsigned u) {
  return __half2float(__ushort_as_half((unsigned short)(u & 0xffff)));
}
__device__ __forceinline__ float unpHi(unsigned u) {
  return __half2float(__ushort_as_half((unsigned short)(u >> 16)));
}
__device__ __forceinline__ unsigned combMM(unsigned A, unsigned B) {
  return packMM(fminf(unpLo(A), unpLo(B)), fmaxf(unpHi(A), unpHi(B)));
}

// Decode pair index q (super-tile-major enumeration of the lower triangle)
// into (ti, tj), ti >= tj. Super-tile = 8x8 tiles; base(SI) = 32*SI^2 + 4*SI.
__device__ __forceinline__ void pair_from_q(int q, int& ti, int& tj) {
  int SI = 0;
  while (32 * (SI + 1) * (SI + 1) + 4 * (SI + 1) <= q) ++SI;
  int r = q - (32 * SI * SI + 4 * SI);
  int i, j, SJ;
  if (r < 64 * SI) {
    SJ = r >> 6;
    int w = r & 63;
    i = w >> 3;
    j = w & 7;
  } else {
    int d = r - 64 * SI;
    SJ = SI;
    i = 0;
    while ((i + 1) * (i + 2) / 2 <= d) ++i;
    j = d - i * (i + 1) / 2;
  }
  ti = SI * 8 + i;
  tj = SJ * 8 + j;
}

// Fragment-major e8 layout: byte (row,k) stored at
//   (row>>4)*8192 + (k>>5)*512 + (row&15)*32 + (k&31)

// ---- kernel 1: L2-normalize rows -> fp8 e4m3 (x16), fragment-major ----
// Also zeroes out[0] (replaces a separate memset dispatch; stream order
// guarantees it precedes finalize_loss's atomicAdd).
__global__ __launch_bounds__(256) void normalize_rows(
    const float* __restrict__ emb, unsigned char* __restrict__ e8,
    float* __restrict__ out) {
  if (blockIdx.x == 0 && threadIdx.x == 0) out[0] = 0.f;
  const int wave = threadIdx.x >> 6, lane = threadIdx.x & 63;
  const int row = blockIdx.x * 4 + wave;
  const float4* src = (const float4*)(emb + (size_t)row * D);
  float4 x0 = src[lane];
  float4 x1 = src[lane + 64];
  float ss = x0.x * x0.x + x0.y * x0.y + x0.z * x0.z + x0.w * x0.w +
             x1.x * x1.x + x1.y * x1.y + x1.z * x1.z + x1.w * x1.w;
#pragma unroll
  for (int m = 1; m < 64; m <<= 1) ss += __shfl_xor(ss, m, 64);
  const float r = rsqrtf(ss) * ESCALE;
  union { unsigned char b[8]; uint2 u; } o;
  o.b[0] = f2fp8(x0.x * r); o.b[1] = f2fp8(x0.y * r);
  o.b[2] = f2fp8(x0.z * r); o.b[3] = f2fp8(x0.w * r);
  o.b[4] = f2fp8(x1.x * r); o.b[5] = f2fp8(x1.y * r);
  o.b[6] = f2fp8(x1.z * r); o.b[7] = f2fp8(x1.w * r);
  const unsigned off = (unsigned)(row >> 4) * 8192 + (unsigned)(lane >> 2) * 512 +
                       (row & 15) * 32 + (lane & 3) * 8;
  *(uint2*)(e8 + off) = o.u;
}

// ---- kernel 2: LDS-free symmetric fp8 Gram GEMM + batch-hard mining ----
// 2080 blocks (pair q = 260*(b%8) + b/8, XCD-wedge, L2-local). K-loop:
// depth-3 rotating register pipeline (4 phases, no copies, no per-chunk
// drain), zero-VALU addressing via per-frag base pointers + imm offsets.
__global__ __launch_bounds__(256, 3) void bh_gemm_sym(
    const unsigned char* __restrict__ e8, const int* __restrict__ labels,
    unsigned* __restrict__ scr) {
  __shared__ unsigned bufR[2][128]; // [wc][row within tile]
  __shared__ unsigned bufC[2][128]; // [wr][col within tile]

  const int b = blockIdx.x;
  const int q = WEDGE * (b & 7) + (b >> 3);
  int ti, tj;
  pair_from_q(q, ti, tj);
  const int iBase = ti * BM, jBase = tj * BN;
  const bool diag = (ti == tj);

  const int tid = threadIdx.x;
  const int lane = tid & 63;
  const int wave = tid >> 6;
  const int wr = wave >> 1, wc = wave & 1;
  const int quad = lane >> 4, n16 = lane & 15;

  const unsigned laneOff = (unsigned)n16 * 32 + (unsigned)quad * 8;
  // per-frag-row base pointers; all K-loop loads use compile-time imm offsets
  const unsigned char* aP[4];
  const unsigned char* bP[4];
#pragma unroll
  for (int r = 0; r < 4; ++r) {
    aP[r] = e8 + (unsigned)(iBase + wr * 64 + r * 16) * 512 + laneOff;
    bP[r] = e8 + (unsigned)(jBase + wc * 64 + r * 16) * 512 + laneOff;
  }

  f32x4 acc[4][4];
#pragma unroll
  for (int r = 0; r < 4; ++r)
#pragma unroll
    for (int c = 0; c < 4; ++c) acc[r][c] = (f32x4)0.0f;

  long abuf[4][4], bbuf[4][4]; // rotating 4-phase register pipeline (depth 3)
#pragma unroll
  for (int ph = 0; ph < 3; ++ph)
#pragma unroll
    for (int r = 0; r < 4; ++r) {
      abuf[ph][r] = *(const long*)(aP[r] + ph * 512);
      bbuf[ph][r] = *(const long*)(bP[r] + ph * 512);
    }

#pragma unroll
  for (int kb = 0; kb < NKB; ++kb) {
    const int cur = kb & 3;
    if (kb + 3 < NKB) {
      const int nxt = (kb + 3) & 3;
#pragma unroll
      for (int r = 0; r < 4; ++r) {
        abuf[nxt][r] = *(const long*)(aP[r] + (kb + 3) * 512);
        bbuf[nxt][r] = *(const long*)(bP[r] + (kb + 3) * 512);
      }
    }
#pragma unroll
    for (int r = 0; r < 4; ++r)
#pragma unroll
      for (int c = 0; c < 4; ++c)
        acc[r][c] = __builtin_amdgcn_mfma_f32_16x16x32_fp8_fp8(
            abuf[cur][r], bbuf[cur][c], acc[r][c], 0, 0, 0);
  }

  // ---- epilogue: batch-hard mining (similarity = acc / ESCALE^2) ----
  // C/D layout: row = wr*64 + r*16 + quad*4 + v, col = wc*64 + c*16 + n16
  int lj[4];
#pragma unroll
  for (int c = 0; c < 4; ++c) lj[c] = labels[jBase + wc * 64 + c * 16 + n16];

  float cminp[4], cmaxn[4]; // col-side (transpose) mining, live across r
#pragma unroll
  for (int c = 0; c < 4; ++c) {
    cminp[c] = __builtin_inff();
    cmaxn[c] = -__builtin_inff();
  }

#pragma unroll
  for (int r = 0; r < 4; ++r) {
    const int rbase = wr * 64 + r * 16 + quad * 4; // row offset within tile
    int4 li = *(const int4*)(labels + iBase + rbase);
    const int* lav = (const int*)&li;
    float minp[4], maxn[4];
#pragma unroll
    for (int v = 0; v < 4; ++v) {
      minp[v] = __builtin_inff();
      maxn[v] = -__builtin_inff();
    }
#pragma unroll
    for (int c = 0; c < 4; ++c) {
      const int col_ = wc * 64 + c * 16 + n16;
#pragma unroll
      for (int v = 0; v < 4; ++v) {
        float s = acc[r][c][v] * INV_SC2;
        bool same = (lav[v] == lj[c]);
        float pv = same ? s : __builtin_inff();
        float nv = same ? -__builtin_inff() : s;
        if (diag && (rbase + v) == col_) pv = __builtin_inff(); // self
        minp[v] = fminf(minp[v], pv);
        maxn[v] = fmaxf(maxn[v], nv);
        cminp[c] = fminf(cminp[c], same ? s : __builtin_inff());
        cmaxn[c] = fmaxf(cmaxn[c], same ? -__builtin_inff() : s);
      }
    }
    // butterfly across the 16 n16-lanes sharing these 4 rows
#pragma unroll
    for (int m = 1; m <= 8; m <<= 1) {
#pragma unroll
      for (int v = 0; v < 4; ++v) {
        minp[v] = fminf(minp[v], __shfl_xor(minp[v], m, 64));
        maxn[v] = fmaxf(maxn[v], __shfl_xor(maxn[v], m, 64));
      }
    }
    if (n16 == 0) {
#pragma unroll
      for (int v = 0; v < 4; ++v)
        bufR[wc][rbase + v] = packMM(minp[v], maxn[v]);
    }
  }

  // col-side (transpose mining): butterfly across the 4 quads
  if (!diag) {
#pragma unroll
    for (int m = 16; m <= 32; m <<= 1) {
#pragma unroll
      for (int c = 0; c < 4; ++c) {
        cminp[c] = fminf(cminp[c], __shfl_xor(cminp[c], m, 64));
        cmaxn[c] = fmaxf(cmaxn[c], __shfl_xor(cmaxn[c], m, 64));
      }
    }
    if (quad == 0) {
#pragma unroll
      for (int c = 0; c < 4; ++c)
        bufC[wr][wc * 64 + c * 16 + n16] = packMM(cminp[c], cmaxn[c]);
    }
  }

  __syncthreads();

  // merge duplicates; one non-atomic store per slot (slot owner = this pair)
  if (wc == 0) { // waves 0 and 2: rows wr*64 + lane
    const int row = wr * 64 + lane;
    scr[(unsigned)(iBase + row) * 64 + tj] = combMM(bufR[0][row], bufR[1][row]);
  }
  if (!diag && wr == 0) { // waves 0 and 1: cols wc*64 + lane
    const int col = wc * 64 + lane;
    scr[(unsigned)(jBase + col) * 64 + ti] = combMM(bufC[0][col], bufC[1][col]);
  }
}

// ---- kernel 3: per-row reduce over 64 slots, then mean of relu ----
__global__ __launch_bounds__(256) void finalize_loss(
    const unsigned* __restrict__ scr, float* __restrict__ out) {
  const int row = blockIdx.x * 256 + threadIdx.x;
  const uint4* p = (const uint4*)(scr + (unsigned)row * 64);
  float mn = __builtin_inff(), mx = -__builtin_inff();
#pragma unroll
  for (int i = 0; i < 16; ++i) {
    uint4 w = p[i];
    mn = fminf(fminf(fminf(mn, unpLo(w.x)), unpLo(w.y)), fminf(unpLo(w.z), unpLo(w.w)));
    mx = fmaxf(fmaxf(fmaxf(mx, unpHi(w.x)), unpHi(w.y)), fmaxf(unpHi(w.z), unpHi(w.w)));
  }
  float loss = mx - mn + MARGIN;       // hardest_pos - hardest_neg + margin
  float sum = loss > 0.f ? loss : 0.f; // relu(-inf) = 0 matches jnp
#pragma unroll
  for (int m = 1; m < 64; m <<= 1) sum += __shfl_xor(sum, m, 64);
  __shared__ float ws4[4];
  const int lane = threadIdx.x & 63, wave = threadIdx.x >> 6;
  if (lane == 0) ws4[wave] = sum;
  __syncthreads();
  if (threadIdx.x == 0)
    atomicAdd(out, (ws4[0] + ws4[1] + ws4[2] + ws4[3]) * (1.0f / N));
}

extern "C" void kernel_launch(void* const* d_in, const int* in_sizes, int n_in,
                              void* d_out, int out_size, void* d_ws, size_t ws_size,
                              hipStream_t stream) {
  const float* emb = (const float*)d_in[0];
  const int* labels = (const int*)d_in[1];
  float* out = (float*)d_out;

  unsigned char* e8 = (unsigned char*)d_ws;                    // [0, 4 MB): fp8 fragment-major
  unsigned* scr = (unsigned*)((char*)d_ws + (size_t)4 * 1024 * 1024); // [4, 6 MB): 8192x64 u32

  normalize_rows<<<N / 4, 256, 0, stream>>>(emb, e8, out); // also zeroes out[0]
  bh_gemm_sym<<<NPAIR, 256, 0, stream>>>(e8, labels, scr);
  finalize_loss<<<N / 256, 256, 0, stream>>>(scr, out);
}